// Round 2
// baseline (271.252 us; speedup 1.0000x reference)
//
#include <hip/hip_runtime.h>
#include <hip/hip_bf16.h>
#include <math.h>

typedef __bf16 bf16x8 __attribute__((ext_vector_type(8)));
typedef float  f32x4  __attribute__((ext_vector_type(4)));

#define MFMA16(A, B, C) __builtin_amdgcn_mfma_f32_16x16x32_bf16(A, B, C, 0, 0, 0)

__device__ __forceinline__ void gload_lds16(const void* g, void* l) {
  __builtin_amdgcn_global_load_lds((const __attribute__((address_space(1))) void*)g,
                                   (__attribute__((address_space(3))) void*)l, 16, 0, 0);
}

// ---- f32 -> bf16 convert (inputs arrive as float32 per the reference) ----
__global__ __launch_bounds__(256) void cvt_f32_bf16(const float* __restrict__ src,
                                                    __bf16* __restrict__ dst, int n) {
  const int i = (blockIdx.x * 256 + threadIdx.x) * 8;
  if (i >= n) return;
  const float4 a = *(const float4*)(src + i);
  const float4 b = *(const float4*)(src + i + 4);
  bf16x8 v;
  v[0] = (__bf16)a.x; v[1] = (__bf16)a.y; v[2] = (__bf16)a.z; v[3] = (__bf16)a.w;
  v[4] = (__bf16)b.x; v[5] = (__bf16)b.y; v[6] = (__bf16)b.z; v[7] = (__bf16)b.w;
  *(bf16x8*)(dst + i) = v;
}

// C[M,N] = A[M,K] * B[N,K]^T (+ bias), bf16 in, f32 accumulate, CT out.
// 128x128 tile, BK=32, 256 threads (4 waves, 2x2), per-wave 64x64 = acc[4][4].
template <bool BIAS, typename CT>
__global__ __launch_bounds__(256) void gemm_bt(const __bf16* __restrict__ A,
                                               const __bf16* __restrict__ B,
                                               const float* __restrict__ bias,
                                               CT* __restrict__ C, int M, int N, int K) {
  // LDS tiles [128][32] bf16, rows = 64B = 4x16B slots.
  // Swizzle: slot' = slot ^ ((row>>1)&3) -> frag-read's 64 lanes spread over bank-quads.
  __shared__ alignas(16) __bf16 As[2][128 * 32];
  __shared__ alignas(16) __bf16 Bs[2][128 * 32];

  const int tid  = threadIdx.x;
  const int lane = tid & 63;
  const int wv   = tid >> 6;
  const int wr   = wv >> 1, wc = wv & 1;
  const int row0 = blockIdx.y * 128;
  const int col0 = blockIdx.x * 128;
  const int NT   = K >> 5;

  f32x4 acc[4][4] = {};

  auto stage = [&](int buf, int kt) {
    const int k0 = kt << 5;
#pragma unroll
    for (int i = 0; i < 2; ++i) {  // A: 8KB = 512 x 16B slots, 2 issues x 256 thr
      const int n    = i * 256 + tid;
      const int row  = n >> 2;
      const int slot = (n & 3) ^ ((row >> 1) & 3);  // inverse-swizzled SOURCE, linear dest
      gload_lds16(A + (size_t)(row0 + row) * K + (k0 + slot * 8),
                  &As[buf][(i * 256 + wv * 64) * 8]);
    }
#pragma unroll
    for (int i = 0; i < 2; ++i) {
      const int n    = i * 256 + tid;
      const int row  = n >> 2;
      const int slot = (n & 3) ^ ((row >> 1) & 3);
      gload_lds16(B + (size_t)(col0 + row) * K + (k0 + slot * 8),
                  &Bs[buf][(i * 256 + wv * 64) * 8]);
    }
  };

  stage(0, 0);
  __syncthreads();
  int cur = 0;
  for (int kt = 0; kt < NT; ++kt) {
    if (kt + 1 < NT) stage(cur ^ 1, kt + 1);

    bf16x8 af[4], bfr[4];
#pragma unroll
    for (int m = 0; m < 4; ++m) {
      const int row  = wr * 64 + m * 16 + (lane & 15);
      const int slot = (lane >> 4) ^ ((row >> 1) & 3);  // swizzled READ
      af[m] = *(const bf16x8*)&As[cur][row * 32 + slot * 8];
    }
#pragma unroll
    for (int n = 0; n < 4; ++n) {
      const int row  = wc * 64 + n * 16 + (lane & 15);
      const int slot = (lane >> 4) ^ ((row >> 1) & 3);
      bfr[n] = *(const bf16x8*)&Bs[cur][row * 32 + slot * 8];
    }
#pragma unroll
    for (int m = 0; m < 4; ++m)
#pragma unroll
      for (int n = 0; n < 4; ++n) acc[m][n] = MFMA16(af[m], bfr[n], acc[m][n]);

    __syncthreads();  // drains staging vmcnt + guards dbuf reuse
    cur ^= 1;
  }

  // Epilogue: C/D layout col=lane&15, row=(lane>>4)*4+reg (m89-verified)
#pragma unroll
  for (int n = 0; n < 4; ++n) {
    const int   col = col0 + wc * 64 + n * 16 + (lane & 15);
    const float bv  = BIAS ? bias[col] : 0.0f;
#pragma unroll
    for (int m = 0; m < 4; ++m) {
      const int rbase = row0 + wr * 64 + m * 16 + ((lane >> 4) << 2);
#pragma unroll
      for (int r = 0; r < 4; ++r)
        C[(size_t)(rbase + r) * N + col] = (CT)(acc[m][n][r] + bv);
    }
  }
}

// Flash-style causal attention over qkv[B*T, 3C] (Q at col h*64, K at 1024+h*64, V at 2048+h*64).
// Block = (b,h, 64 q-rows); 4 waves x 16 q-rows; KV tiles of 64, double-buffered.
__global__ __launch_bounds__(256) void attn_fwd(const __bf16* __restrict__ qkv,
                                                __bf16* __restrict__ yo) {
  __shared__ alignas(16) __bf16 Ks[2][64 * 64];  // [key][d], 128B rows, slot' = slot ^ (key&7)
  __shared__ alignas(16) __bf16 Vt[2][64 * 64];  // [d][key] transposed, slot' = slot ^ (d&7)
  __shared__ alignas(16) __bf16 Ps[4][16 * 64];  // per-wave P [qrow][key], slot' = slot ^ (qrow&7)

  const int tid  = threadIdx.x;
  const int lane = tid & 63;
  const int wv   = tid >> 6;
  const int b    = blockIdx.y >> 4;
  const int h    = blockIdx.y & 15;
  const int q0   = blockIdx.x * 64;
  const int qw   = q0 + wv * 16;
  const int NT   = blockIdx.x + 1;  // causal: kv tiles 0..q0/64

  const size_t  rs = 3072;
  const __bf16* Qg = qkv + (size_t)b * 2048 * rs + h * 64;
  const __bf16* Kg = Qg + 1024;
  const __bf16* Vg = Qg + 2048;

  // Q A-frags in registers (row = lane&15, k-chunk = lane>>4, contiguous 8)
  bf16x8 aQ[2];
#pragma unroll
  for (int ks = 0; ks < 2; ++ks)
    aQ[ks] = *(const bf16x8*)(Qg + (size_t)(qw + (lane & 15)) * rs + ks * 32 + ((lane >> 4) << 3));

  f32x4 o[4] = {};
  float m_run[4], l_run[4];
#pragma unroll
  for (int r = 0; r < 4; ++r) { m_run[r] = -INFINITY; l_run[r] = 0.0f; }

  auto stageK = [&](int buf, int t) {
    const int k0 = t << 6;
#pragma unroll
    for (int i = 0; i < 2; ++i) {
      const int n    = i * 256 + tid;
      const int row  = n >> 3;
      const int slot = (n & 7) ^ (row & 7);
      gload_lds16(Kg + (size_t)(k0 + row) * rs + slot * 8, &Ks[buf][(i * 256 + wv * 64) * 8]);
    }
  };
  auto stageV = [&](int buf, int t) {  // reg-staged transpose: V[key][d] -> Vt[d][key]
    const int k0 = t << 6;
#pragma unroll
    for (int i = 0; i < 2; ++i) {
      const int n   = i * 256 + tid;
      const int key = n >> 3;
      const int dg  = n & 7;
      bf16x8    v   = *(const bf16x8*)(Vg + (size_t)(k0 + key) * rs + dg * 8);
#pragma unroll
      for (int e = 0; e < 8; ++e) {
        const int d = dg * 8 + e;
        Vt[buf][d * 64 + (((key >> 3) ^ (d & 7)) << 3) + (key & 7)] = v[e];
      }
    }
  };

  stageK(0, 0);
  stageV(0, 0);
  __syncthreads();
  int cur = 0;
  for (int t = 0; t < NT; ++t) {
    const int k0 = t << 6;
    if (t + 1 < NT) { stageK(cur ^ 1, t + 1); stageV(cur ^ 1, t + 1); }

    // S = Q K^T : 4 key-blocks x 2 k-steps
    f32x4 sc[4] = {};
#pragma unroll
    for (int n = 0; n < 4; ++n) {
#pragma unroll
      for (int ks = 0; ks < 2; ++ks) {
        const int krow = n * 16 + (lane & 15);
        const int slot = ((ks << 2) + (lane >> 4)) ^ (krow & 7);
        bf16x8    kf   = *(const bf16x8*)&Ks[cur][krow * 64 + slot * 8];
        sc[n]          = MFMA16(aQ[ks], kf, sc[n]);
      }
    }

    // online softmax (f32). rows = qw + (lane>>4)*4 + r, cols = k0 + n*16 + (lane&15)
    float sv[4][4], rmax[4], rsum[4], lsc[4];
#pragma unroll
    for (int r = 0; r < 4; ++r) {
      const int q  = qw + ((lane >> 4) << 2) + r;
      float     mx = -INFINITY;
#pragma unroll
      for (int n = 0; n < 4; ++n) {
        const int k = k0 + n * 16 + (lane & 15);
        float     s = sc[n][r] * 0.125f;  // 1/sqrt(64)
        if (k > q) s = -INFINITY;         // causal mask
        sv[r][n] = s;
        mx       = fmaxf(mx, s);
      }
      rmax[r] = mx;
    }
#pragma unroll
    for (int off = 8; off >= 1; off >>= 1)
#pragma unroll
      for (int r = 0; r < 4; ++r) rmax[r] = fmaxf(rmax[r], __shfl_xor(rmax[r], off, 64));

#pragma unroll
    for (int r = 0; r < 4; ++r) {
      const float mnew = fmaxf(m_run[r], rmax[r]);  // rmax always finite (key k0 <= q)
      lsc[r]           = expf(m_run[r] - mnew);
      m_run[r]         = mnew;
      float su         = 0.0f;
#pragma unroll
      for (int n = 0; n < 4; ++n) {
        const float p = expf(sv[r][n] - mnew);
        sv[r][n]      = p;
        su += p;
      }
      rsum[r] = su;
    }
#pragma unroll
    for (int off = 8; off >= 1; off >>= 1)
#pragma unroll
      for (int r = 0; r < 4; ++r) rsum[r] += __shfl_xor(rsum[r], off, 64);
#pragma unroll
    for (int r = 0; r < 4; ++r) l_run[r] = l_run[r] * lsc[r] + rsum[r];
#pragma unroll
    for (int n = 0; n < 4; ++n)
#pragma unroll
      for (int r = 0; r < 4; ++r) o[n][r] *= lsc[r];

    // P -> per-wave LDS (bf16, swizzled) for transposition into A-frags
#pragma unroll
    for (int r = 0; r < 4; ++r) {
      const int prow = ((lane >> 4) << 2) + r;
#pragma unroll
      for (int n = 0; n < 4; ++n) {
        const int col = n * 16 + (lane & 15);
        Ps[wv][prow * 64 + (((col >> 3) ^ (prow & 7)) << 3) + (col & 7)] = (__bf16)sv[r][n];
      }
    }
    __syncthreads();  // orders Ps/Vt writes -> reads; drains staging

    // O += P V
#pragma unroll
    for (int ks = 0; ks < 2; ++ks) {
      const int prow = lane & 15;
      const int slot = ((ks << 2) + (lane >> 4)) ^ (prow & 7);
      bf16x8    pf   = *(const bf16x8*)&Ps[wv][prow * 64 + slot * 8];
#pragma unroll
      for (int n = 0; n < 4; ++n) {
        const int d     = n * 16 + (lane & 15);
        const int slotv = ((ks << 2) + (lane >> 4)) ^ (d & 7);
        bf16x8    vf    = *(const bf16x8*)&Vt[cur][d * 64 + slotv * 8];
        o[n]            = MFMA16(pf, vf, o[n]);
      }
    }
    __syncthreads();  // all reads of cur done before restage
    cur ^= 1;
  }

  // normalize + write y_att[b*T+q][h*64+d]
#pragma unroll
  for (int n = 0; n < 4; ++n) {
    const int d = n * 16 + (lane & 15);
#pragma unroll
    for (int r = 0; r < 4; ++r) {
      const int q = qw + ((lane >> 4) << 2) + r;
      yo[((size_t)b * 2048 + q) * 1024 + h * 64 + d] = (__bf16)(o[n][r] / l_run[r]);
    }
  }
}

extern "C" void kernel_launch(void* const* d_in, const int* in_sizes, int n_in, void* d_out,
                              int out_size, void* d_ws, size_t ws_size, hipStream_t stream) {
  (void)in_sizes; (void)n_in; (void)out_size; (void)ws_size;
  const float* x     = (const float*)d_in[0];   // [2,2048,1024] f32
  const float* w_qkv = (const float*)d_in[1];   // [3072,1024]   f32
  const float* w_out = (const float*)d_in[2];   // [1024,1024]   f32
  const float* b_out = (const float*)d_in[3];   // [1024]        f32
  float*       out   = (float*)d_out;           // [2,2048,1024] f32

  __bf16* xb    = (__bf16*)d_ws;                        // 4096*1024
  __bf16* wqkvb = xb + (size_t)4096 * 1024;             // 3072*1024
  __bf16* woutb = wqkvb + (size_t)3072 * 1024;          // 1024*1024
  __bf16* qkv   = woutb + (size_t)1024 * 1024;          // 4096*3072
  __bf16* yatt  = qkv + (size_t)4096 * 3072;            // 4096*1024  (total ~50.3 MB)

  // 0) convert f32 inputs to bf16
  cvt_f32_bf16<<<(4096 * 1024) / (256 * 8), 256, 0, stream>>>(x, xb, 4096 * 1024);
  cvt_f32_bf16<<<(3072 * 1024) / (256 * 8), 256, 0, stream>>>(w_qkv, wqkvb, 3072 * 1024);
  cvt_f32_bf16<<<(1024 * 1024) / (256 * 8), 256, 0, stream>>>(w_out, woutb, 1024 * 1024);

  // 1) qkv = x @ w_qkv^T           (M=4096, N=3072, K=1024)
  gemm_bt<false, __bf16><<<dim3(24, 32), 256, 0, stream>>>(xb, wqkvb, nullptr, qkv,
                                                           4096, 3072, 1024);
  // 2) causal multi-head attention (grid: 32 q-tiles x 32 (b,h))
  attn_fwd<<<dim3(32, 32), 256, 0, stream>>>(qkv, yatt);
  // 3) out = y_att @ w_out^T + b   (M=4096, N=1024, K=1024), f32 output
  gemm_bt<true, float><<<dim3(8, 32), 256, 0, stream>>>(yatt, woutb, b_out, out,
                                                        4096, 1024, 1024);
}

// Round 3
// 145.013 us; speedup vs baseline: 1.8705x; 1.8705x over previous
//
#include <hip/hip_runtime.h>
#include <hip/hip_bf16.h>
#include <math.h>

typedef __bf16 bf16x8 __attribute__((ext_vector_type(8)));
typedef float  f32x4  __attribute__((ext_vector_type(4)));

#define MFMA16(A, B, C) __builtin_amdgcn_mfma_f32_16x16x32_bf16(A, B, C, 0, 0, 0)

__device__ __forceinline__ void gload_lds16(const void* g, void* l) {
  __builtin_amdgcn_global_load_lds((const __attribute__((address_space(1))) void*)g,
                                   (__attribute__((address_space(3))) void*)l, 16, 0, 0);
}

__device__ __forceinline__ float exp2_fast(float x) {  // 2^x; x=-inf -> 0
  float r; asm("v_exp_f32 %0, %1" : "=v"(r) : "v"(x)); return r;
}

// ---- f32 -> bf16 convert (inputs arrive as float32 per the reference) ----
__global__ __launch_bounds__(256) void cvt_f32_bf16(const float* __restrict__ src,
                                                    __bf16* __restrict__ dst, int n) {
  const int i = (blockIdx.x * 256 + threadIdx.x) * 8;
  if (i >= n) return;
  const float4 a = *(const float4*)(src + i);
  const float4 b = *(const float4*)(src + i + 4);
  bf16x8 v;
  v[0] = (__bf16)a.x; v[1] = (__bf16)a.y; v[2] = (__bf16)a.z; v[3] = (__bf16)a.w;
  v[4] = (__bf16)b.x; v[5] = (__bf16)b.y; v[6] = (__bf16)b.z; v[7] = (__bf16)b.w;
  *(bf16x8*)(dst + i) = v;
}

// C[M,N] = A[M,K] * B[N,K]^T (+ bias), bf16 in, f32 accumulate, CT out.
template <bool BIAS, typename CT>
__global__ __launch_bounds__(256) void gemm_bt(const __bf16* __restrict__ A,
                                               const __bf16* __restrict__ B,
                                               const float* __restrict__ bias,
                                               CT* __restrict__ C, int M, int N, int K) {
  __shared__ alignas(16) __bf16 As[2][128 * 32];
  __shared__ alignas(16) __bf16 Bs[2][128 * 32];

  const int tid  = threadIdx.x;
  const int lane = tid & 63;
  const int wv   = tid >> 6;
  const int wr   = wv >> 1, wc = wv & 1;
  const int row0 = blockIdx.y * 128;
  const int col0 = blockIdx.x * 128;
  const int NT   = K >> 5;

  f32x4 acc[4][4] = {};

  auto stage = [&](int buf, int kt) {
    const int k0 = kt << 5;
#pragma unroll
    for (int i = 0; i < 2; ++i) {
      const int n    = i * 256 + tid;
      const int row  = n >> 2;
      const int slot = (n & 3) ^ ((row >> 1) & 3);  // inverse-swizzled SOURCE, linear dest
      gload_lds16(A + (size_t)(row0 + row) * K + (k0 + slot * 8),
                  &As[buf][(i * 256 + wv * 64) * 8]);
    }
#pragma unroll
    for (int i = 0; i < 2; ++i) {
      const int n    = i * 256 + tid;
      const int row  = n >> 2;
      const int slot = (n & 3) ^ ((row >> 1) & 3);
      gload_lds16(B + (size_t)(col0 + row) * K + (k0 + slot * 8),
                  &Bs[buf][(i * 256 + wv * 64) * 8]);
    }
  };

  stage(0, 0);
  __syncthreads();
  int cur = 0;
  for (int kt = 0; kt < NT; ++kt) {
    if (kt + 1 < NT) stage(cur ^ 1, kt + 1);

    bf16x8 af[4], bfr[4];
#pragma unroll
    for (int m = 0; m < 4; ++m) {
      const int row  = wr * 64 + m * 16 + (lane & 15);
      const int slot = (lane >> 4) ^ ((row >> 1) & 3);  // swizzled READ
      af[m] = *(const bf16x8*)&As[cur][row * 32 + slot * 8];
    }
#pragma unroll
    for (int n = 0; n < 4; ++n) {
      const int row  = wc * 64 + n * 16 + (lane & 15);
      const int slot = (lane >> 4) ^ ((row >> 1) & 3);
      bfr[n] = *(const bf16x8*)&Bs[cur][row * 32 + slot * 8];
    }
#pragma unroll
    for (int m = 0; m < 4; ++m)
#pragma unroll
      for (int n = 0; n < 4; ++n) acc[m][n] = MFMA16(af[m], bfr[n], acc[m][n]);

    __syncthreads();
    cur ^= 1;
  }

#pragma unroll
  for (int n = 0; n < 4; ++n) {
    const int   col = col0 + wc * 64 + n * 16 + (lane & 15);
    const float bv  = BIAS ? bias[col] : 0.0f;
#pragma unroll
    for (int m = 0; m < 4; ++m) {
      const int rbase = row0 + wr * 64 + m * 16 + ((lane >> 4) << 2);
#pragma unroll
      for (int r = 0; r < 4; ++r)
        C[(size_t)(rbase + r) * N + col] = (CT)(acc[m][n][r] + bv);
    }
  }
}

// Flash-style causal attention. Grid (16, 32): block x handles q-tiles {x, 31-x}
// sequentially -> uniform 33 tile-iters/block (load balance). 4 waves x 16 q-rows.
// One barrier per KV tile. Row-sum via MFMA ones-block (Vt rows 64..79 == 1).
__global__ __launch_bounds__(256) void attn_fwd(const __bf16* __restrict__ qkv,
                                                __bf16* __restrict__ yo) {
  __shared__ alignas(16) __bf16 Ks[2][64 * 64];  // [key][d], slot' = slot ^ (key&7)
  __shared__ alignas(16) __bf16 Vt[2][80 * 64];  // [d][key] transposed + 16 ones-rows
  __shared__ alignas(16) __bf16 Ps[4][16 * 64];  // per-wave P, slot' per (qrow,colgrp)

  const int tid  = threadIdx.x;
  const int lane = tid & 63;
  const int wv   = tid >> 6;
  const int b    = blockIdx.y >> 4;
  const int h    = blockIdx.y & 15;

  const size_t  rs = 3072;
  const __bf16* Qg = qkv + (size_t)b * 2048 * rs + h * 64;
  const __bf16* Kg = Qg + 1024;
  const __bf16* Vg = Qg + 2048;

  // constant ones rows d=64..79 of both Vt buffers (row-sum trick; swizzle-invariant)
  for (int idx = tid; idx < 2048; idx += 256) {
    const int buf = idx >> 10, rr = idx & 1023;
    Vt[buf][(64 + (rr >> 6)) * 64 + (rr & 63)] = (__bf16)1.0f;
  }

  bf16x8 vreg[2];  // in-flight V tile (T14 async-stage: load early, LDS-write late)

  auto loadV = [&](int t) {
#pragma unroll
    for (int i = 0; i < 2; ++i) {
      const int n = i * 256 + tid, key = n >> 3, dg = n & 7;
      vreg[i] = *(const bf16x8*)(Vg + (size_t)((t << 6) + key) * rs + dg * 8);
    }
  };
  // Store V transposed into Vt[buf]. Element-store order XOR-rotated by dg so each
  // store instruction's 64 lanes hit 64 distinct addr&63 positions (conflict-free);
  // read layout (slot = kchunk ^ (d&7)) unchanged.
  auto storeV = [&](int buf) {
#pragma unroll
    for (int i = 0; i < 2; ++i) {
      const int n = i * 256 + tid, key = n >> 3, dg = n & 7;
      union { bf16x8 v; unsigned int w[4]; unsigned short hh[8]; } u;
      u.v = vreg[i];
      // xor-permute elements by dg: after this, u.hh[s] == v[s ^ dg]
      {
        const bool c1 = dg & 1, c2 = dg & 2, c4 = dg & 4;
        unsigned r0 = (u.w[0] >> 16) | (u.w[0] << 16);
        unsigned r1 = (u.w[1] >> 16) | (u.w[1] << 16);
        unsigned r2 = (u.w[2] >> 16) | (u.w[2] << 16);
        unsigned r3 = (u.w[3] >> 16) | (u.w[3] << 16);
        u.w[0] = c1 ? r0 : u.w[0]; u.w[1] = c1 ? r1 : u.w[1];
        u.w[2] = c1 ? r2 : u.w[2]; u.w[3] = c1 ? r3 : u.w[3];
        unsigned s0 = u.w[0], s1 = u.w[1], s2 = u.w[2], s3 = u.w[3];
        u.w[0] = c2 ? s1 : s0; u.w[1] = c2 ? s0 : s1;
        u.w[2] = c2 ? s3 : s2; u.w[3] = c2 ? s2 : s3;
        s0 = u.w[0]; s1 = u.w[1]; s2 = u.w[2]; s3 = u.w[3];
        u.w[0] = c4 ? s2 : s0; u.w[1] = c4 ? s3 : s1;
        u.w[2] = c4 ? s0 : s2; u.w[3] = c4 ? s1 : s3;
      }
      const int kc = key >> 3;  // wave-uniform
      const int j  = key & 7;
#pragma unroll
      for (int s = 0; s < 8; ++s) {
        const int e = s ^ dg;           // = d&7, varies across lanes per step
        const int d = dg * 8 + e;
        unsigned short hv = u.hh[s];
        __bf16 bv; __builtin_memcpy(&bv, &hv, 2);
        Vt[buf][d * 64 + ((kc ^ e) & 7) * 8 + j] = bv;
      }
    }
  };
  auto stageK = [&](int buf, int t) {
#pragma unroll
    for (int i = 0; i < 2; ++i) {
      const int n = i * 256 + tid, row = n >> 3, slot = (n & 7) ^ (row & 7);
      gload_lds16(Kg + (size_t)((t << 6) + row) * rs + slot * 8,
                  &Ks[buf][(i * 256 + wv * 64) * 8]);
    }
  };

  const float SCALE2 = 0.125f * 1.44269504088896f;  // 1/sqrt(64) * log2(e)

#pragma unroll 1
  for (int seg = 0; seg < 2; ++seg) {
    const int qt = seg ? (31 - (int)blockIdx.x) : (int)blockIdx.x;
    const int q0 = qt * 64;
    const int qw = q0 + wv * 16;
    const int NT = qt + 1;

    bf16x8 aQ[2];
#pragma unroll
    for (int ks = 0; ks < 2; ++ks)
      aQ[ks] = *(const bf16x8*)(Qg + (size_t)(qw + (lane & 15)) * rs + ks * 32 +
                                ((lane >> 4) << 3));

    f32x4 o[5] = {};  // o[4] accumulates row-sum (ones-block)
    float m2[4];
#pragma unroll
    for (int r = 0; r < 4; ++r) m2[r] = -INFINITY;

    int cur = 0;
    stageK(0, 0);
    loadV(0);
    storeV(0);
    __syncthreads();

    for (int t = 0; t < NT; ++t) {
      const int  k0  = t << 6;
      const bool pre = (t + 1 < NT);
      if (pre) { stageK(cur ^ 1, t + 1); loadV(t + 1); }  // async issues, consumed late

      // S = Q K^T
      f32x4 sc[4] = {};
      __builtin_amdgcn_s_setprio(1);
#pragma unroll
      for (int n = 0; n < 4; ++n) {
#pragma unroll
        for (int ks = 0; ks < 2; ++ks) {
          const int krow = n * 16 + (lane & 15);
          const int slot = ((ks << 2) + (lane >> 4)) ^ (krow & 7);
          bf16x8    kf   = *(const bf16x8*)&Ks[cur][krow * 64 + slot * 8];
          sc[n]          = MFMA16(aQ[ks], kf, sc[n]);
        }
      }
      __builtin_amdgcn_s_setprio(0);

      // online softmax, base-2. rows = qw+(lane>>4)*4+r, cols = k0+n*16+(lane&15)
      float sv[4][4], rmax[4];
      if (t == NT - 1) {  // only the diagonal tile needs masking (uniform branch)
#pragma unroll
        for (int r = 0; r < 4; ++r) {
          const int q  = qw + ((lane >> 4) << 2) + r;
          float     mx = -INFINITY;
#pragma unroll
          for (int n = 0; n < 4; ++n) {
            const int k = k0 + n * 16 + (lane & 15);
            float     s = sc[n][r] * SCALE2;
            if (k > q) s = -INFINITY;
            sv[r][n] = s;
            mx       = fmaxf(mx, s);
          }
          rmax[r] = mx;
        }
      } else {
#pragma unroll
        for (int r = 0; r < 4; ++r) {
          float mx = -INFINITY;
#pragma unroll
          for (int n = 0; n < 4; ++n) {
            const float s = sc[n][r] * SCALE2;
            sv[r][n]      = s;
            mx            = fmaxf(mx, s);
          }
          rmax[r] = mx;
        }
      }
#pragma unroll
      for (int off = 8; off >= 1; off >>= 1)
#pragma unroll
        for (int r = 0; r < 4; ++r) rmax[r] = fmaxf(rmax[r], __shfl_xor(rmax[r], off, 64));

      float lscv[4];
#pragma unroll
      for (int r = 0; r < 4; ++r) {
        const float mnew = fmaxf(m2[r], rmax[r]);
        lscv[r]          = exp2_fast(m2[r] - mnew);
        m2[r]            = mnew;
#pragma unroll
        for (int n = 0; n < 4; ++n) sv[r][n] = exp2_fast(sv[r][n] - mnew);
      }
#pragma unroll
      for (int n = 0; n < 5; ++n)
#pragma unroll
        for (int r = 0; r < 4; ++r) o[n][r] *= lscv[r];

      // P -> per-wave LDS (bf16, swizzled); intra-wave, no barrier needed
#pragma unroll
      for (int r = 0; r < 4; ++r) {
        const int prow = ((lane >> 4) << 2) + r;
#pragma unroll
        for (int n = 0; n < 4; ++n) {
          const int col = n * 16 + (lane & 15);
          Ps[wv][prow * 64 + (((col >> 3) ^ (prow & 7)) << 3) + (col & 7)] =
              (__bf16)sv[r][n];
        }
      }

      if (pre) storeV(cur ^ 1);  // T14: HBM latency hidden under QK^T+softmax

      // O += P V  (n=4 block: ones -> row-sum into o[4])
      __builtin_amdgcn_s_setprio(1);
#pragma unroll
      for (int ks = 0; ks < 2; ++ks) {
        const int prow = lane & 15;
        const int slot = ((ks << 2) + (lane >> 4)) ^ (prow & 7);
        bf16x8    pf   = *(const bf16x8*)&Ps[wv][prow * 64 + slot * 8];
#pragma unroll
        for (int n = 0; n < 5; ++n) {
          const int d     = n * 16 + (lane & 15);
          const int slotv = ((ks << 2) + (lane >> 4)) ^ (d & 7);
          bf16x8    vf    = *(const bf16x8*)&Vt[cur][d * 64 + slotv * 8];
          o[n]            = MFMA16(pf, vf, o[n]);
        }
      }
      __builtin_amdgcn_s_setprio(0);

      __syncthreads();  // single barrier: guards dbuf swap + staging visibility
      cur ^= 1;
    }

    // normalize (l = o[4]) + write y_att[b*T+q][h*64+d]
#pragma unroll
    for (int n = 0; n < 4; ++n) {
      const int d = n * 16 + (lane & 15);
#pragma unroll
      for (int r = 0; r < 4; ++r) {
        const int q = qw + ((lane >> 4) << 2) + r;
        yo[((size_t)b * 2048 + q) * 1024 + h * 64 + d] = (__bf16)(o[n][r] / o[4][r]);
      }
    }
  }
}

extern "C" void kernel_launch(void* const* d_in, const int* in_sizes, int n_in, void* d_out,
                              int out_size, void* d_ws, size_t ws_size, hipStream_t stream) {
  (void)in_sizes; (void)n_in; (void)out_size; (void)ws_size;
  const float* x     = (const float*)d_in[0];
  const float* w_qkv = (const float*)d_in[1];
  const float* w_out = (const float*)d_in[2];
  const float* b_out = (const float*)d_in[3];
  float*       out   = (float*)d_out;

  __bf16* xb    = (__bf16*)d_ws;
  __bf16* wqkvb = xb + (size_t)4096 * 1024;
  __bf16* woutb = wqkvb + (size_t)3072 * 1024;
  __bf16* qkv   = woutb + (size_t)1024 * 1024;
  __bf16* yatt  = qkv + (size_t)4096 * 3072;

  cvt_f32_bf16<<<(4096 * 1024) / (256 * 8), 256, 0, stream>>>(x, xb, 4096 * 1024);
  cvt_f32_bf16<<<(3072 * 1024) / (256 * 8), 256, 0, stream>>>(w_qkv, wqkvb, 3072 * 1024);
  cvt_f32_bf16<<<(1024 * 1024) / (256 * 8), 256, 0, stream>>>(w_out, woutb, 1024 * 1024);

  gemm_bt<false, __bf16><<<dim3(24, 32), 256, 0, stream>>>(xb, wqkvb, nullptr, qkv,
                                                           4096, 3072, 1024);
  attn_fwd<<<dim3(16, 32), 256, 0, stream>>>(qkv, yatt);
  gemm_bt<true, float><<<dim3(8, 32), 256, 0, stream>>>(yatt, woutb, b_out, out,
                                                        4096, 1024, 1024);
}